// Round 9
// baseline (173.648 us; speedup 1.0000x reference)
//
#include <hip/hip_runtime.h>
#include <math.h>

#define Bv   8192
#define EPSv 1e-5f
#define CONFv 0.1f
#define MB (1024*1024)

typedef __attribute__((ext_vector_type(8))) short short8;
typedef __attribute__((ext_vector_type(4))) float f32x4;

__device__ __forceinline__ float wave_sum64(float v){
  #pragma unroll
  for (int o = 32; o; o >>= 1) v += __shfl_xor(v, o, 64);
  return v;
}

__device__ __forceinline__ void split3f(float x, short &h, short &m, short &l){
  unsigned u = __float_as_uint(x);
  h = (short)(u >> 16);
  float r1 = x - __uint_as_float(u & 0xffff0000u);
  unsigned u1 = __float_as_uint(r1);
  m = (short)(u1 >> 16);
  float r2 = r1 - __uint_as_float(u1 & 0xffff0000u);
  l = (short)(__float_as_uint(r2) >> 16);
}

__device__ __forceinline__ void split2f(float x, short &h, short &m){
  unsigned u = __float_as_uint(x);
  h = (short)(u >> 16);
  float r1 = x - __uint_as_float(u & 0xffff0000u);
  m = (short)(__float_as_uint(r1) >> 16);
}

// 5-pass: A 2-plane (h,m) x B 3-plane. Error ~2^-24-class.
__device__ __forceinline__ f32x4 mfma5(short8 ah, short8 am,
                                       short8 bh, short8 bm, short8 bl, f32x4 c){
  c = __builtin_amdgcn_mfma_f32_16x16x32_bf16(am, bm, c, 0, 0, 0);
  c = __builtin_amdgcn_mfma_f32_16x16x32_bf16(ah, bl, c, 0, 0, 0);
  c = __builtin_amdgcn_mfma_f32_16x16x32_bf16(am, bh, c, 0, 0, 0);
  c = __builtin_amdgcn_mfma_f32_16x16x32_bf16(ah, bm, c, 0, 0, 0);
  c = __builtin_amdgcn_mfma_f32_16x16x32_bf16(ah, bh, c, 0, 0, 0);
  return c;
}

__device__ __forceinline__ f32x4 mfma3(short8 ah, short8 al,
                                       short8 bh, short8 bl, f32x4 c){
  c = __builtin_amdgcn_mfma_f32_16x16x32_bf16(al, bh, c, 0, 0, 0);
  c = __builtin_amdgcn_mfma_f32_16x16x32_bf16(ah, bl, c, 0, 0, 0);
  c = __builtin_amdgcn_mfma_f32_16x16x32_bf16(ah, bh, c, 0, 0, 0);
  return c;
}

// ---------------- kernel 1: rp-path packing + p2E pack + cnt zero (R5) ----
__global__ __launch_bounds__(256) void k_pre(
    const float* __restrict__ w1, const float* __restrict__ w2,
    const float* __restrict__ opw, const float* __restrict__ pw2,
    unsigned short* __restrict__ w1p, unsigned short* __restrict__ w2p,
    unsigned short* __restrict__ opwp, unsigned short* __restrict__ p2,
    int* __restrict__ cnt)
{
  int bid = blockIdx.x;
  if (bid < 128){
    int gid = bid*256 + threadIdx.x;                  // 32768, K=128, N=256
    int k = gid >> 8, n = gid & 255;
    short h, m, l;
    split3f(w1[gid], h, m, l);
    int idx = (((n >> 4)*4 + (k >> 5))*64 + (((k >> 3) & 3)*16 + (n & 15)))*8 + (k & 7);
    w1p[idx]             = (unsigned short)h;
    w1p[32768 + idx]     = (unsigned short)m;
    w1p[2*32768 + idx]   = (unsigned short)l;
  } else if (bid < 640){
    int gid = (bid - 128)*256 + threadIdx.x;          // 131072, K=256, N=512
    int k = gid >> 9, n = gid & 511;
    short h, m, l;
    split3f(w2[gid], h, m, l);
    int idx = (((n >> 4)*8 + (k >> 5))*64 + (((k >> 3) & 3)*16 + (n & 15)))*8 + (k & 7);
    w2p[idx]             = (unsigned short)h;
    w2p[131072 + idx]    = (unsigned short)m;
    w2p[2*131072 + idx]  = (unsigned short)l;
  } else if (bid < 768){
    int gid = (bid - 640)*256 + threadIdx.x;          // 32768, K=512, N=64
    int k = gid >> 6, n = gid & 63;
    short h, m, l;
    split3f(opw[gid], h, m, l);
    int idx = (((n >> 4)*16 + (k >> 5))*64 + (((k >> 3) & 3)*16 + (n & 15)))*8 + (k & 7);
    opwp[idx]            = (unsigned short)h;
    opwp[32768 + idx]    = (unsigned short)m;
    opwp[2*32768 + idx]  = (unsigned short)l;
  } else if (bid < 896){
    int t = (bid - 768)*256 + threadIdx.x;            // [0, 32768)  pe_w2 pack
    int e = t >> 9, rem = t & 511, kg = rem >> 4, n = rem & 15;
    const float* src = pw2 + (size_t)e*4096 + (size_t)(kg*8)*16 + n;
    short8 h, l;
    #pragma unroll
    for (int j = 0; j < 8; j++){
      float w = src[(size_t)j*16];
      unsigned u = __float_as_uint(w);
      float r2 = w - __uint_as_float(u & 0xffff0000u);
      h[j] = (short)(u >> 16);
      l[j] = (short)(__float_as_uint(r2) >> 16);
    }
    int idx8 = (((kg >> 2)*64) + (kg & 3)*16 + n) << 3;
    unsigned short* ep = p2 + (size_t)e * 8192;
    *(short8*)(ep + idx8)        = h;
    *(short8*)(ep + 4096 + idx8) = l;
  } else {
    if (threadIdx.x < 64) cnt[threadIdx.x] = 0;
  }
}

// ---------------- kernel 2: fused rp1->rp2->gate, M=16, 512 blocks --------
// Half-size blocks (M=16, 32KB dyn LDS + ~7KB static, 1024 thr) -> 2 blocks
// co-resident per CU, overlapping each other's barrier/reducer stalls.
// (R8 counters: 1 block/CU, MfmaUtil 13%, occ 33% -> latency-bound.)
__global__ __launch_bounds__(1024) void k_fused(const float* __restrict__ X,
    const unsigned short* __restrict__ w1p, const float* __restrict__ b1,
    const float* __restrict__ g1, const float* __restrict__ be1,
    const unsigned short* __restrict__ w2p, const float* __restrict__ b2,
    const float* __restrict__ g2, const float* __restrict__ be2,
    const unsigned short* __restrict__ opwp, const float* __restrict__ opb,
    unsigned short* __restrict__ fh, unsigned short* __restrict__ fl,
    float* __restrict__ dout, int* __restrict__ cnt, int* __restrict__ list)
{
  extern __shared__ unsigned char smem[];
  unsigned short* xh  = (unsigned short*)smem;          // [16][128]
  unsigned short* xm  = xh + 2048;
  unsigned short* hbh = xh + 4096;                      // [16][256]
  unsigned short* hbm = xh + 8192;
  unsigned short* gah = xh;                             // [16][512] overlay
  unsigned short* gam = xh + 8192;
  __shared__ float ps[16][20];
  __shared__ float pq[16][20];
  __shared__ float mi[16][2];
  __shared__ float lg[16][64];

  const int tid = threadIdx.x;
  const int r0  = blockIdx.x * 16;
  const int wave = tid >> 6, lane = tid & 63, lquad = lane >> 4, l15 = lane & 15;

  if (tid < 512){
    int r = tid >> 5, c4 = tid & 31;
    float4 v = ((const float4*)X)[(size_t)(r0+r)*32 + c4];
    unsigned u0 = __float_as_uint(v.x), u1 = __float_as_uint(v.y);
    unsigned u2 = __float_as_uint(v.z), u3 = __float_as_uint(v.w);
    float m0 = v.x - __uint_as_float(u0 & 0xffff0000u);
    float m1 = v.y - __uint_as_float(u1 & 0xffff0000u);
    float m2 = v.z - __uint_as_float(u2 & 0xffff0000u);
    float m3 = v.w - __uint_as_float(u3 & 0xffff0000u);
    unsigned hp0 = (u0 >> 16) | (u1 & 0xffff0000u);
    unsigned hp1 = (u2 >> 16) | (u3 & 0xffff0000u);
    unsigned mp0 = (__float_as_uint(m0) >> 16) | (__float_as_uint(m1) & 0xffff0000u);
    unsigned mp1 = (__float_as_uint(m2) >> 16) | (__float_as_uint(m3) & 0xffff0000u);
    int gk = c4 >> 1, half = c4 & 1;
    int off = r*128 + ((gk ^ (r & 7)) << 3) + half*4;
    ((unsigned*)(xh + off))[0] = hp0;
    ((unsigned*)(xh + off))[1] = hp1;
    ((unsigned*)(xm + off))[0] = mp0;
    ((unsigned*)(xm + off))[1] = mp1;
  }
  __syncthreads();

  float bcol1, gcol1, becol1;
  {
    int col = wave*16 + l15;
    bcol1 = b1[col]; gcol1 = g1[col]; becol1 = be1[col];
  }
  {
    f32x4 acc = (f32x4){0.f,0.f,0.f,0.f};
    const int pstride = 32768;
    for (int ks4 = 0; ks4 < 4; ks4++){
      const unsigned short* bp = w1p + (((wave*4 + ks4)*64 + lane) << 3);
      short8 bh = *(const short8*)bp;
      short8 bm = *(const short8*)(bp + pstride);
      short8 bl = *(const short8*)(bp + 2*pstride);
      int r = l15;
      int off = r*128 + (((ks4*4 + lquad) ^ (r & 7)) << 3);
      short8 ah = *(const short8*)(xh + off);
      short8 am = *(const short8*)(xm + off);
      acc = mfma5(ah, am, bh, bm, bl, acc);
    }
    #pragma unroll
    for (int reg = 0; reg < 4; reg++){
      float z = acc[reg] + bcol1;
      float s = z, q = z*z;
      #pragma unroll
      for (int o = 1; o < 16; o <<= 1){ s += __shfl_xor(s, o, 64); q += __shfl_xor(q, o, 64); }
      int row = lquad*4 + reg;
      if (l15 == 0){ ps[row][wave] = s; pq[row][wave] = q; }
    }
    __syncthreads();
    if (tid < 16){
      int row = tid;
      float4 s0 = *(const float4*)&ps[row][0],  s1 = *(const float4*)&ps[row][4];
      float4 s2 = *(const float4*)&ps[row][8],  s3 = *(const float4*)&ps[row][12];
      float4 q0 = *(const float4*)&pq[row][0],  q1 = *(const float4*)&pq[row][4];
      float4 q2 = *(const float4*)&pq[row][8],  q3 = *(const float4*)&pq[row][12];
      float s = s0.x; s += s0.y; s += s0.z; s += s0.w;
      s += s1.x; s += s1.y; s += s1.z; s += s1.w;
      s += s2.x; s += s2.y; s += s2.z; s += s2.w;
      s += s3.x; s += s3.y; s += s3.z; s += s3.w;
      float q = q0.x; q += q0.y; q += q0.z; q += q0.w;
      q += q1.x; q += q1.y; q += q1.z; q += q1.w;
      q += q2.x; q += q2.y; q += q2.z; q += q2.w;
      q += q3.x; q += q3.y; q += q3.z; q += q3.w;
      float mean = s * (1.0f/256.0f);
      float var  = q * (1.0f/256.0f) - mean*mean;
      mi[row][0] = mean;
      mi[row][1] = 1.0f / sqrtf(var + EPSv);
    }
    __syncthreads();
    #pragma unroll
    for (int reg = 0; reg < 4; reg++){
      int row = lquad*4 + reg;
      float2 mv = *(const float2*)mi[row];
      int col = wave*16 + l15;
      float z = acc[reg] + bcol1;
      float y = fmaxf((z - mv.x)*mv.y*gcol1 + becol1, 0.f);
      short hh, mm2;
      split2f(y, hh, mm2);
      int gg = col >> 3, c7 = col & 7;
      int adr = row*256 + ((gg ^ (row & 7)) << 3) + c7;
      hbh[adr] = (unsigned short)hh;
      hbm[adr] = (unsigned short)mm2;
    }
  }
  __syncthreads();

  f32x4 acc2[2];
  acc2[0] = (f32x4){0.f,0.f,0.f,0.f};
  acc2[1] = (f32x4){0.f,0.f,0.f,0.f};
  {
    const int pstride = 131072;
    for (int ks4 = 0; ks4 < 8; ks4++){
      int r = l15;
      int off = r*256 + (((ks4*4 + lquad) ^ (r & 7)) << 3);
      short8 ah = *(const short8*)(hbh + off);
      short8 am = *(const short8*)(hbm + off);
      #pragma unroll
      for (int nt = 0; nt < 2; nt++){
        int ntg = wave*2 + nt;
        const unsigned short* bp = w2p + (((ntg*8 + ks4)*64 + lane) << 3);
        short8 bh = *(const short8*)bp;
        short8 bm = *(const short8*)(bp + pstride);
        short8 bl = *(const short8*)(bp + 2*pstride);
        acc2[nt] = mfma5(ah, am, bh, bm, bl, acc2[nt]);
      }
    }
  }

  float bcol[2], gcol[2], becol[2];
  #pragma unroll
  for (int nt = 0; nt < 2; nt++){
    int col = (wave*2 + nt)*16 + l15;
    bcol[nt] = b2[col]; gcol[nt] = g2[col]; becol[nt] = be2[col];
  }
  #pragma unroll
  for (int reg = 0; reg < 4; reg++){
    float s = 0.f, q = 0.f;
    #pragma unroll
    for (int nt = 0; nt < 2; nt++){
      float z = acc2[nt][reg] + bcol[nt];
      s += z; q += z*z;
    }
    #pragma unroll
    for (int o = 1; o < 16; o <<= 1){ s += __shfl_xor(s, o, 64); q += __shfl_xor(q, o, 64); }
    int row = lquad*4 + reg;
    if (l15 == 0){ ps[row][wave] = s; pq[row][wave] = q; }
  }
  __syncthreads();
  if (tid < 16){
    int row = tid;
    float4 s0 = *(const float4*)&ps[row][0],  s1 = *(const float4*)&ps[row][4];
    float4 s2 = *(const float4*)&ps[row][8],  s3 = *(const float4*)&ps[row][12];
    float4 q0 = *(const float4*)&pq[row][0],  q1 = *(const float4*)&pq[row][4];
    float4 q2 = *(const float4*)&pq[row][8],  q3 = *(const float4*)&pq[row][12];
    float s = s0.x; s += s0.y; s += s0.z; s += s0.w;
    s += s1.x; s += s1.y; s += s1.z; s += s1.w;
    s += s2.x; s += s2.y; s += s2.z; s += s2.w;
    s += s3.x; s += s3.y; s += s3.z; s += s3.w;
    float q = q0.x; q += q0.y; q += q0.z; q += q0.w;
    q += q1.x; q += q1.y; q += q1.z; q += q1.w;
    q += q2.x; q += q2.y; q += q2.z; q += q2.w;
    q += q3.x; q += q3.y; q += q3.z; q += q3.w;
    float mean = s * (1.0f/512.0f);
    float var  = q * (1.0f/512.0f) - mean*mean;
    mi[row][0] = mean;
    mi[row][1] = 1.0f / sqrtf(var + EPSv);
  }
  __syncthreads();

  #pragma unroll
  for (int reg = 0; reg < 4; reg++){
    int row = lquad*4 + reg;
    float2 mv = *(const float2*)mi[row];
    #pragma unroll
    for (int nt = 0; nt < 2; nt++){
      int col = (wave*2 + nt)*16 + l15;
      float z = acc2[nt][reg] + bcol[nt];
      float y = fmaxf((z - mv.x)*mv.y*gcol[nt] + becol[nt], 0.f);
      short hh, mm2;
      split2f(y, hh, mm2);
      int gg = col >> 3, c7 = col & 7;
      int adr = row*512 + ((gg ^ (row & 7)) << 3) + c7;
      gah[adr] = (unsigned short)hh;
      gam[adr] = (unsigned short)mm2;
    }
  }
  __syncthreads();

  if (wave < 4){
    f32x4 accg = (f32x4){0.f,0.f,0.f,0.f};
    for (int kt = 0; kt < 16; kt++){
      const unsigned short* bp = opwp + (((wave*16 + kt)*64 + lane) << 3);
      short8 bh = *(const short8*)bp;
      short8 bm = *(const short8*)(bp + 32768);
      short8 bl = *(const short8*)(bp + 65536);
      int r = l15;
      int off = r*512 + (((kt*4 + lquad) ^ (r & 7)) << 3);
      short8 ah = *(const short8*)(gah + off);
      short8 am = *(const short8*)(gam + off);
      accg = mfma5(ah, am, bh, bm, bl, accg);
    }
    float opbv = opb[wave*16 + l15];
    #pragma unroll
    for (int reg = 0; reg < 4; reg++)
      lg[lquad*4 + reg][wave*16 + l15] = accg[reg] + opbv;
  } else {
    int t4 = (wave - 4)*64 + lane;
    for (int i = t4; i < 2048; i += 768){
      int p = i >> 10, rem = i & 1023, r = rem >> 6, gg = rem & 63;
      short8 v = *(const short8*)((p ? gam : gah) + r*512 + ((gg ^ (r & 7)) << 3));
      unsigned short* dst = (p ? fl : fh) + (size_t)(r0 + r)*512 + gg*8;
      *(short8*)dst = v;
    }
  }
  __syncthreads();

  {
    int r = wave, row = r0 + r;
    float l = lg[r][lane];
    float mx = l;
    #pragma unroll
    for (int o = 32; o; o >>= 1) mx = fmaxf(mx, __shfl_xor(mx, o, 64));
    float p = expf(l - mx);
    float s = wave_sum64(p);
    p /= s;
    float pv = p;
    for (int j = 0; j < 3; j++){
      float v = pv; int idx = lane;
      #pragma unroll
      for (int o = 32; o; o >>= 1){
        float ov = __shfl_xor(v, o, 64);
        int   oi = __shfl_xor(idx, o, 64);
        if (ov > v || (ov == v && oi < idx)){ v = ov; idx = oi; }
      }
      if (lane == 0){
        dout[(size_t)row*3 + j]                = v;
        dout[(size_t)Bv*3 + (size_t)row*3 + j] = (float)idx;
      }
      if (v >= CONFv){
        if (lane == 0){
          int pos = atomicAdd(&cnt[idx], 1);
          list[idx*Bv + pos] = (row << 2) | j;
        }
      } else {
        if (lane < 16) dout[(size_t)Bv*6 + (size_t)row*48 + j*16 + lane] = 0.f;
      }
      if (lane == idx) pv = -1.0f;
    }
  }
}

// ---------------- kernel 3: expert MLP, M=64 tile, direct fp32 weights ----
// (exact R5 body — best measured config)
__global__ __launch_bounds__(1024) void k_expert(const unsigned short* __restrict__ fh,
    const unsigned short* __restrict__ fl,
    const float* __restrict__ pw1, const float* __restrict__ b1,
    const float* __restrict__ g,  const float* __restrict__ beta,
    const unsigned short* __restrict__ p2, const float* __restrict__ b2,
    const int* __restrict__ cnt,  const int* __restrict__ list,
    float* __restrict__ dout)
{
  __shared__ unsigned short xbuf[65536];             // xh [64][512] | xl [64][512]
  unsigned short* xh = xbuf;
  unsigned short* xl = xbuf + 32768;
  unsigned short* zp = xbuf;                         // overlay [64][528] hi/lo
  __shared__ float ps[64][16];
  __shared__ float pq[64][16];
  __shared__ float mi[64][2];
  __shared__ int sdesc[3];

  const int tid = threadIdx.x;
  const int wave = tid >> 6, lane = tid & 63;
  const int lquad = lane >> 4, l15 = lane & 15;

  if (wave == 0){
    int c  = cnt[lane];
    int tl = (c + 63) >> 6;
    int incl = tl;
    #pragma unroll
    for (int o = 1; o < 64; o <<= 1){
      int v = __shfl_up(incl, o, 64);
      if (lane >= o) incl += v;
    }
    int total = __shfl(incl, 63, 64);
    int G   = (total + 7) >> 3;
    int grp = blockIdx.x & 7, rr = blockIdx.x >> 3;
    int lgc = grp*G + rr;
    int ok  = (G > 0) && (rr < G) && (lgc < total);
    unsigned long long bm = __ballot(ok && (incl > lgc));
    if (lane == 0){
      if (!ok || bm == 0ull){ sdesc[0] = -1; }
      else {
        int e = __ffsll((long long)bm) - 1;
        sdesc[0] = e; sdesc[1] = lgc; sdesc[2] = 0;
      }
    }
    if (bm != 0ull && ok){
      int e = __ffsll((long long)bm) - 1;
      int excl = __shfl(incl - tl, e, 64);
      int ne   = __shfl(c, e, 64);
      if (lane == 0){ sdesc[1] = lgc - excl; sdesc[2] = ne; }
    }
  }
  __syncthreads();
  const int e = sdesc[0];
  if (e < 0) return;
  const int t = sdesc[1];
  const int n = sdesc[2];
  const int base = t * 64;
  const int m = min(64, n - base);
  const int* lrow = list + e*Bv + base;

  // ---- stage feats hi/lo planes (64 rows) -> swizzled LDS
  for (int i = tid; i < 8192; i += 1024){
    int p = i >> 12, rem = i & 4095, r = rem >> 6, gg = rem & 63;
    int ev = lrow[(r < m) ? r : 0];
    int row = ev >> 2;
    const unsigned short* src = (p ? fl : fh) + (size_t)row*512 + gg*8;
    short8 v = *(const short8*)src;
    unsigned short* dst = (p ? xl : xh) + r*512 + ((gg ^ (r & 7)) << 3);
    *(short8*)dst = v;
  }
  __syncthreads();

  // ---- GEMM1: M=64, N=256, K=512; wave w owns ntile w (16 cols), 4 mtiles
  const float* bw = pw1 + (size_t)e*131072 + wave*16 + l15;
  f32x4 acc[4];
  #pragma unroll
  for (int mt = 0; mt < 4; mt++) acc[mt] = (f32x4){0.f,0.f,0.f,0.f};

  for (int kt = 0; kt < 16; kt++){
    const float* bk = bw + (size_t)(kt*32 + lquad*8)*256;
    float wv[8];
    #pragma unroll
    for (int j = 0; j < 8; j++) wv[j] = bk[(size_t)j*256];
    short8 bh, bl;
    #pragma unroll
    for (int j = 0; j < 8; j++){
      unsigned u = __float_as_uint(wv[j]);
      float r2 = wv[j] - __uint_as_float(u & 0xffff0000u);
      bh[j] = (short)(u >> 16);
      bl[j] = (short)(__float_as_uint(r2) >> 16);
    }
    int gk = kt*4 + lquad;
    #pragma unroll
    for (int mt = 0; mt < 4; mt++){
      int r = mt*16 + l15;
      int off = r*512 + ((gk ^ (r & 7)) << 3);
      short8 ah = *(const short8*)(xh + off);
      short8 al = *(const short8*)(xl + off);
      acc[mt] = mfma3(ah, al, bh, bl, acc[mt]);
    }
  }

  // ---- bias + LN partials (each wave: 16-col partial for its ntile)
  float bb, gv, bv;
  {
    int col = wave*16 + l15;
    bb = b1[e*256 + col];
    gv = g[e*256 + col];
    bv = beta[e*256 + col];
  }
  #pragma unroll
  for (int mt = 0; mt < 4; mt++)
    #pragma unroll
    for (int reg = 0; reg < 4; reg++){
      float z = acc[mt][reg] + bb;
      float s = z, q = z*z;
      #pragma unroll
      for (int o = 1; o < 16; o <<= 1){ s += __shfl_xor(s, o, 64); q += __shfl_xor(q, o, 64); }
      int row = mt*16 + lquad*4 + reg;
      if (l15 == 0){ ps[row][wave] = s; pq[row][wave] = q; }
    }
  __syncthreads();   // all xh/xl reads done -> zp overlay safe
  if (tid < 64){
    int row = tid;
    float s = 0.f, q = 0.f;
    #pragma unroll
    for (int c4 = 0; c4 < 4; c4++){
      float4 sv = *(const float4*)&ps[row][c4*4];
      float4 qv = *(const float4*)&pq[row][c4*4];
      s += sv.x + sv.y + sv.z + sv.w;
      q += qv.x + qv.y + qv.z + qv.w;
    }
    float mean = s * (1.0f/256.0f);
    float var  = q * (1.0f/256.0f) - mean*mean;
    mi[row][0] = mean;
    mi[row][1] = 1.0f / sqrtf(var + EPSv);
  }
  __syncthreads();

  // ---- LN finalize + ReLU -> zp hi/lo planes (row stride 528)
  #pragma unroll
  for (int mt = 0; mt < 4; mt++)
    #pragma unroll
    for (int reg = 0; reg < 4; reg++){
      int row = mt*16 + lquad*4 + reg;
      float2 mv = *(const float2*)mi[row];
      int col = wave*16 + l15;
      float z = acc[mt][reg] + bb;
      float y = fmaxf((z - mv.x)*mv.y*gv + bv, 0.f);
      short hh, mm2;
      split2f(y, hh, mm2);
      zp[row*528 + col]       = (unsigned short)hh;
      zp[row*528 + 264 + col] = (unsigned short)mm2;
    }
  __syncthreads();

  // ---- GEMM2: 64x16, K=256, 3-pass; waves 0..3 handle 16 rows each
  if (wave < 4){
    const unsigned short* p2e = p2 + (size_t)e * 8192;
    f32x4 acc2 = (f32x4){0.f,0.f,0.f,0.f};
    for (int kt2 = 0; kt2 < 8; kt2++){
      const unsigned short* zb = zp + (wave*16 + l15)*528 + kt2*32 + lquad*8;
      short8 ahh = *(const short8*)zb;
      short8 all2 = *(const short8*)(zb + 264);
      const unsigned short* bp = p2e + ((kt2*64 + lane) << 3);
      short8 bh = *(const short8*)bp;
      short8 bl = *(const short8*)(bp + 4096);
      acc2 = mfma3(ahh, all2, bh, bl, acc2);
    }
    float b2v = b2[e*16 + l15];
    #pragma unroll
    for (int reg = 0; reg < 4; reg++){
      int rl = wave*16 + lquad*4 + reg;
      if (rl < m){
        int ev = lrow[rl];
        int row = ev >> 2, j = ev & 3;
        dout[(size_t)Bv*6 + (size_t)row*48 + j*16 + l15] = acc2[reg] + b2v;
      }
    }
  }
}

extern "C" void kernel_launch(void* const* d_in, const int* in_sizes, int n_in,
                              void* d_out, int out_size, void* d_ws, size_t ws_size,
                              hipStream_t stream)
{
  const float* X   = (const float*)d_in[0];
  const float* w1  = (const float*)d_in[1];
  const float* b1  = (const float*)d_in[2];
  const float* g1  = (const float*)d_in[3];
  const float* be1 = (const float*)d_in[4];
  const float* w2  = (const float*)d_in[5];
  const float* b2  = (const float*)d_in[6];
  const float* g2  = (const float*)d_in[7];
  const float* be2 = (const float*)d_in[8];
  const float* opw = (const float*)d_in[9];
  const float* opb = (const float*)d_in[10];
  const float* pw1 = (const float*)d_in[11];
  const float* pb1 = (const float*)d_in[12];
  const float* pg  = (const float*)d_in[13];
  const float* pbe = (const float*)d_in[14];
  const float* pw2 = (const float*)d_in[15];
  const float* pb2 = (const float*)d_in[16];
  float* out = (float*)d_out;
  char*  ws  = (char*)d_ws;

  unsigned short* p2E    = (unsigned short*)(ws + (size_t)32*MB);
  unsigned short* w1p_rp = (unsigned short*)(ws + (size_t)33*MB);
  unsigned short* w2p_rp = (unsigned short*)(ws + (size_t)34*MB);
  unsigned short* opwp   = (unsigned short*)(ws + (size_t)35*MB);
  unsigned short* fh     = (unsigned short*)(ws + (size_t)36*MB);
  unsigned short* fl     = (unsigned short*)(ws + (size_t)44*MB);
  int*            list   = (int*)(ws + (size_t)52*MB);
  int*            cnt    = (int*)(ws + (size_t)54*MB);

  k_pre   <<<897, 256, 0, stream>>>(w1, w2, opw, pw2,
                                    w1p_rp, w2p_rp, opwp, p2E, cnt);
  k_fused <<<512, 1024, 32768, stream>>>(X, w1p_rp, b1, g1, be1,
                                         w2p_rp, b2, g2, be2, opwp, opb,
                                         fh, fl, out, cnt, list);
  k_expert<<<448, 1024, 0, stream>>>(fh, fl, pw1, pb1, pg, pbe, p2E, pb2,
                                     cnt, list, out);
}

// Round 10
// 169.584 us; speedup vs baseline: 1.0240x; 1.0240x over previous
//
#include <hip/hip_runtime.h>
#include <math.h>

#define Bv   8192
#define EPSv 1e-5f
#define CONFv 0.1f
#define MB (1024*1024)

typedef __attribute__((ext_vector_type(8))) short short8;
typedef __attribute__((ext_vector_type(4))) float f32x4;

__device__ __forceinline__ float wave_sum64(float v){
  #pragma unroll
  for (int o = 32; o; o >>= 1) v += __shfl_xor(v, o, 64);
  return v;
}

__device__ __forceinline__ void split3f(float x, short &h, short &m, short &l){
  unsigned u = __float_as_uint(x);
  h = (short)(u >> 16);
  float r1 = x - __uint_as_float(u & 0xffff0000u);
  unsigned u1 = __float_as_uint(r1);
  m = (short)(u1 >> 16);
  float r2 = r1 - __uint_as_float(u1 & 0xffff0000u);
  l = (short)(__float_as_uint(r2) >> 16);
}

__device__ __forceinline__ void split2f(float x, short &h, short &m){
  unsigned u = __float_as_uint(x);
  h = (short)(u >> 16);
  float r1 = x - __uint_as_float(u & 0xffff0000u);
  m = (short)(__float_as_uint(r1) >> 16);
}

// 5-pass: A 2-plane (h,m) x B 3-plane. Error ~2^-24-class.
__device__ __forceinline__ f32x4 mfma5(short8 ah, short8 am,
                                       short8 bh, short8 bm, short8 bl, f32x4 c){
  c = __builtin_amdgcn_mfma_f32_16x16x32_bf16(am, bm, c, 0, 0, 0);
  c = __builtin_amdgcn_mfma_f32_16x16x32_bf16(ah, bl, c, 0, 0, 0);
  c = __builtin_amdgcn_mfma_f32_16x16x32_bf16(am, bh, c, 0, 0, 0);
  c = __builtin_amdgcn_mfma_f32_16x16x32_bf16(ah, bm, c, 0, 0, 0);
  c = __builtin_amdgcn_mfma_f32_16x16x32_bf16(ah, bh, c, 0, 0, 0);
  return c;
}

__device__ __forceinline__ f32x4 mfma3(short8 ah, short8 al,
                                       short8 bh, short8 bl, f32x4 c){
  c = __builtin_amdgcn_mfma_f32_16x16x32_bf16(al, bh, c, 0, 0, 0);
  c = __builtin_amdgcn_mfma_f32_16x16x32_bf16(ah, bl, c, 0, 0, 0);
  c = __builtin_amdgcn_mfma_f32_16x16x32_bf16(ah, bh, c, 0, 0, 0);
  return c;
}

// ---------------- kernel 1: p2E pack + cnt zero (tiny) --------------------
// rp-weight packing is GONE: k_fused reads w1/w2/opw directly (packed
// 3-plane = 6B/weight > 4B fp32 source — R5's lesson applied to rp path).
__global__ __launch_bounds__(256) void k_pre(
    const float* __restrict__ pw2, unsigned short* __restrict__ p2,
    int* __restrict__ cnt)
{
  int bid = blockIdx.x;
  if (bid < 128){
    int t = bid*256 + threadIdx.x;                    // [0, 32768)  pe_w2 pack
    int e = t >> 9, rem = t & 511, kg = rem >> 4, n = rem & 15;
    const float* src = pw2 + (size_t)e*4096 + (size_t)(kg*8)*16 + n;
    short8 h, l;
    #pragma unroll
    for (int j = 0; j < 8; j++){
      float w = src[(size_t)j*16];
      unsigned u = __float_as_uint(w);
      float r2 = w - __uint_as_float(u & 0xffff0000u);
      h[j] = (short)(u >> 16);
      l[j] = (short)(__float_as_uint(r2) >> 16);
    }
    int idx8 = (((kg >> 2)*64) + (kg & 3)*16 + n) << 3;
    unsigned short* ep = p2 + (size_t)e * 8192;
    *(short8*)(ep + idx8)        = h;
    *(short8*)(ep + 4096 + idx8) = l;
  } else {
    if (threadIdx.x < 64) cnt[threadIdx.x] = 0;
  }
}

// ---------------- kernel 2: fused rp1->rp2->gate, 256 blocks --------------
// Direct fp32 weight reads + on-the-fly split3f (bit-identical to packed
// path). Lanes read consecutive n -> coalesced; bytes/block 1.18MB->786KB.
__global__ __launch_bounds__(1024) void k_fused(const float* __restrict__ X,
    const float* __restrict__ w1, const float* __restrict__ b1,
    const float* __restrict__ g1, const float* __restrict__ be1,
    const float* __restrict__ w2, const float* __restrict__ b2,
    const float* __restrict__ g2, const float* __restrict__ be2,
    const float* __restrict__ opw, const float* __restrict__ opb,
    unsigned short* __restrict__ fh, unsigned short* __restrict__ fl,
    float* __restrict__ dout, int* __restrict__ cnt, int* __restrict__ list)
{
  extern __shared__ unsigned char smem[];
  unsigned short* xh  = (unsigned short*)smem;          // [32][128]
  unsigned short* xm  = xh + 4096;
  unsigned short* hbh = xh + 8192;                      // [32][256]
  unsigned short* hbm = xh + 16384;
  unsigned short* gah = xh;                             // [32][512] overlay
  unsigned short* gam = xh + 16384;
  __shared__ float ps[32][20];
  __shared__ float pq[32][20];
  __shared__ float mi[32][2];
  __shared__ float lg[32][64];

  const int tid = threadIdx.x;
  const int r0  = blockIdx.x * 32;
  const int wave = tid >> 6, lane = tid & 63, lquad = lane >> 4, l15 = lane & 15;

  {
    int r = tid >> 5, c4 = tid & 31;
    float4 v = ((const float4*)X)[(size_t)(r0+r)*32 + c4];
    unsigned u0 = __float_as_uint(v.x), u1 = __float_as_uint(v.y);
    unsigned u2 = __float_as_uint(v.z), u3 = __float_as_uint(v.w);
    float m0 = v.x - __uint_as_float(u0 & 0xffff0000u);
    float m1 = v.y - __uint_as_float(u1 & 0xffff0000u);
    float m2 = v.z - __uint_as_float(u2 & 0xffff0000u);
    float m3 = v.w - __uint_as_float(u3 & 0xffff0000u);
    unsigned hp0 = (u0 >> 16) | (u1 & 0xffff0000u);
    unsigned hp1 = (u2 >> 16) | (u3 & 0xffff0000u);
    unsigned mp0 = (__float_as_uint(m0) >> 16) | (__float_as_uint(m1) & 0xffff0000u);
    unsigned mp1 = (__float_as_uint(m2) >> 16) | (__float_as_uint(m3) & 0xffff0000u);
    int gk = c4 >> 1, half = c4 & 1;
    int off = r*128 + ((gk ^ (r & 7)) << 3) + half*4;
    ((unsigned*)(xh + off))[0] = hp0;
    ((unsigned*)(xh + off))[1] = hp1;
    ((unsigned*)(xm + off))[0] = mp0;
    ((unsigned*)(xm + off))[1] = mp1;
  }
  __syncthreads();

  float bcol1, gcol1, becol1;
  {
    int col = wave*16 + l15;
    bcol1 = b1[col]; gcol1 = g1[col]; becol1 = be1[col];
  }
  {
    f32x4 acc[2];
    acc[0] = (f32x4){0.f,0.f,0.f,0.f};
    acc[1] = (f32x4){0.f,0.f,0.f,0.f};
    for (int ks4 = 0; ks4 < 4; ks4++){
      // B: w1[k][n], k = ks4*32 + lquad*8 + j, n = wave*16 + l15
      const float* bk = w1 + (size_t)(ks4*32 + lquad*8)*256 + wave*16 + l15;
      float wv[8];
      #pragma unroll
      for (int j = 0; j < 8; j++) wv[j] = bk[(size_t)j*256];
      short8 bh, bm, bl;
      #pragma unroll
      for (int j = 0; j < 8; j++){
        short h, m, l;
        split3f(wv[j], h, m, l);
        bh[j] = h; bm[j] = m; bl[j] = l;
      }
      #pragma unroll
      for (int mt = 0; mt < 2; mt++){
        int r = mt*16 + l15;
        int off = r*128 + (((ks4*4 + lquad) ^ (r & 7)) << 3);
        short8 ah = *(const short8*)(xh + off);
        short8 am = *(const short8*)(xm + off);
        acc[mt] = mfma5(ah, am, bh, bm, bl, acc[mt]);
      }
    }
    #pragma unroll
    for (int mt = 0; mt < 2; mt++)
      #pragma unroll
      for (int reg = 0; reg < 4; reg++){
        float z = acc[mt][reg] + bcol1;
        float s = z, q = z*z;
        #pragma unroll
        for (int o = 1; o < 16; o <<= 1){ s += __shfl_xor(s, o, 64); q += __shfl_xor(q, o, 64); }
        int row = mt*16 + lquad*4 + reg;
        if (l15 == 0){ ps[row][wave] = s; pq[row][wave] = q; }
      }
    __syncthreads();
    if (tid < 32){
      int row = tid;
      float4 s0 = *(const float4*)&ps[row][0],  s1 = *(const float4*)&ps[row][4];
      float4 s2 = *(const float4*)&ps[row][8],  s3 = *(const float4*)&ps[row][12];
      float4 q0 = *(const float4*)&pq[row][0],  q1 = *(const float4*)&pq[row][4];
      float4 q2 = *(const float4*)&pq[row][8],  q3 = *(const float4*)&pq[row][12];
      float s = s0.x; s += s0.y; s += s0.z; s += s0.w;
      s += s1.x; s += s1.y; s += s1.z; s += s1.w;
      s += s2.x; s += s2.y; s += s2.z; s += s2.w;
      s += s3.x; s += s3.y; s += s3.z; s += s3.w;
      float q = q0.x; q += q0.y; q += q0.z; q += q0.w;
      q += q1.x; q += q1.y; q += q1.z; q += q1.w;
      q += q2.x; q += q2.y; q += q2.z; q += q2.w;
      q += q3.x; q += q3.y; q += q3.z; q += q3.w;
      float mean = s * (1.0f/256.0f);
      float var  = q * (1.0f/256.0f) - mean*mean;
      mi[row][0] = mean;
      mi[row][1] = 1.0f / sqrtf(var + EPSv);
    }
    __syncthreads();
    #pragma unroll
    for (int mt = 0; mt < 2; mt++)
      #pragma unroll
      for (int reg = 0; reg < 4; reg++){
        int row = mt*16 + lquad*4 + reg;
        float2 mv = *(const float2*)mi[row];
        int col = wave*16 + l15;
        float z = acc[mt][reg] + bcol1;
        float y = fmaxf((z - mv.x)*mv.y*gcol1 + becol1, 0.f);
        short hh, mm2;
        split2f(y, hh, mm2);
        int gg = col >> 3, c7 = col & 7;
        int adr = row*256 + ((gg ^ (row & 7)) << 3) + c7;
        hbh[adr] = (unsigned short)hh;
        hbm[adr] = (unsigned short)mm2;
      }
  }
  __syncthreads();

  f32x4 acc2[2][2];
  #pragma unroll
  for (int mt = 0; mt < 2; mt++)
    #pragma unroll
    for (int nt = 0; nt < 2; nt++) acc2[mt][nt] = (f32x4){0.f,0.f,0.f,0.f};
  {
    for (int ks4 = 0; ks4 < 8; ks4++){
      short8 ah[2], am[2];
      #pragma unroll
      for (int mt = 0; mt < 2; mt++){
        int r = mt*16 + l15;
        int off = r*256 + (((ks4*4 + lquad) ^ (r & 7)) << 3);
        ah[mt] = *(const short8*)(hbh + off);
        am[mt] = *(const short8*)(hbm + off);
      }
      #pragma unroll
      for (int nt = 0; nt < 2; nt++){
        // B: w2[k][n], k = ks4*32 + lquad*8 + j, n = (wave*2+nt)*16 + l15
        const float* bk = w2 + (size_t)(ks4*32 + lquad*8)*512 + (wave*2 + nt)*16 + l15;
        float wv[8];
        #pragma unroll
        for (int j = 0; j < 8; j++) wv[j] = bk[(size_t)j*512];
        short8 bh, bm, bl;
        #pragma unroll
        for (int j = 0; j < 8; j++){
          short h, m, l;
          split3f(wv[j], h, m, l);
          bh[j] = h; bm[j] = m; bl[j] = l;
        }
        #pragma unroll
        for (int mt = 0; mt < 2; mt++)
          acc2[mt][nt] = mfma5(ah[mt], am[mt], bh, bm, bl, acc2[mt][nt]);
      }
    }
  }

  float bcol[2], gcol[2], becol[2];
  #pragma unroll
  for (int nt = 0; nt < 2; nt++){
    int col = (wave*2 + nt)*16 + l15;
    bcol[nt] = b2[col]; gcol[nt] = g2[col]; becol[nt] = be2[col];
  }
  #pragma unroll
  for (int mt = 0; mt < 2; mt++)
    #pragma unroll
    for (int reg = 0; reg < 4; reg++){
      float s = 0.f, q = 0.f;
      #pragma unroll
      for (int nt = 0; nt < 2; nt++){
        float z = acc2[mt][nt][reg] + bcol[nt];
        s += z; q += z*z;
      }
      #pragma unroll
      for (int o = 1; o < 16; o <<= 1){ s += __shfl_xor(s, o, 64); q += __shfl_xor(q, o, 64); }
      int row = mt*16 + lquad*4 + reg;
      if (l15 == 0){ ps[row][wave] = s; pq[row][wave] = q; }
    }
  __syncthreads();
  if (tid < 32){
    int row = tid;
    float4 s0 = *(const float4*)&ps[row][0],  s1 = *(const float4*)&ps[row][4];
    float4 s2 = *(const float4*)&ps[row][8],  s3 = *(const float4*)&ps[row][12];
    float4 q0 = *(const float4*)&pq[row][0],  q1 = *(const float4*)&pq[row][4];
    float4 q2 = *(const float4*)&pq[row][8],  q3 = *(const float4*)&pq[row][12];
    float s = s0.x; s += s0.y; s += s0.z; s += s0.w;
    s += s1.x; s += s1.y; s += s1.z; s += s1.w;
    s += s2.x; s += s2.y; s += s2.z; s += s2.w;
    s += s3.x; s += s3.y; s += s3.z; s += s3.w;
    float q = q0.x; q += q0.y; q += q0.z; q += q0.w;
    q += q1.x; q += q1.y; q += q1.z; q += q1.w;
    q += q2.x; q += q2.y; q += q2.z; q += q2.w;
    q += q3.x; q += q3.y; q += q3.z; q += q3.w;
    float mean = s * (1.0f/512.0f);
    float var  = q * (1.0f/512.0f) - mean*mean;
    mi[row][0] = mean;
    mi[row][1] = 1.0f / sqrtf(var + EPSv);
  }
  __syncthreads();

  #pragma unroll
  for (int mt = 0; mt < 2; mt++)
    #pragma unroll
    for (int reg = 0; reg < 4; reg++){
      int row = mt*16 + lquad*4 + reg;
      float2 mv = *(const float2*)mi[row];
      #pragma unroll
      for (int nt = 0; nt < 2; nt++){
        int col = (wave*2 + nt)*16 + l15;
        float z = acc2[mt][nt][reg] + bcol[nt];
        float y = fmaxf((z - mv.x)*mv.y*gcol[nt] + becol[nt], 0.f);
        short hh, mm2;
        split2f(y, hh, mm2);
        int gg = col >> 3, c7 = col & 7;
        int adr = row*512 + ((gg ^ (row & 7)) << 3) + c7;
        gah[adr] = (unsigned short)hh;
        gam[adr] = (unsigned short)mm2;
      }
    }
  __syncthreads();

  if (wave < 4){
    f32x4 accg[2];
    accg[0] = (f32x4){0.f,0.f,0.f,0.f};
    accg[1] = (f32x4){0.f,0.f,0.f,0.f};
    for (int kt = 0; kt < 16; kt++){
      // B: opw[k][n], k = kt*32 + lquad*8 + j, n = wave*16 + l15
      const float* bk = opw + (size_t)(kt*32 + lquad*8)*64 + wave*16 + l15;
      float wv[8];
      #pragma unroll
      for (int j = 0; j < 8; j++) wv[j] = bk[(size_t)j*64];
      short8 bh, bm, bl;
      #pragma unroll
      for (int j = 0; j < 8; j++){
        short h, m, l;
        split3f(wv[j], h, m, l);
        bh[j] = h; bm[j] = m; bl[j] = l;
      }
      #pragma unroll
      for (int mt = 0; mt < 2; mt++){
        int r = mt*16 + l15;
        int off = r*512 + (((kt*4 + lquad) ^ (r & 7)) << 3);
        short8 ah = *(const short8*)(gah + off);
        short8 am = *(const short8*)(gam + off);
        accg[mt] = mfma5(ah, am, bh, bm, bl, accg[mt]);
      }
    }
    float opbv = opb[wave*16 + l15];
    #pragma unroll
    for (int mt = 0; mt < 2; mt++)
      #pragma unroll
      for (int reg = 0; reg < 4; reg++)
        lg[mt*16 + lquad*4 + reg][wave*16 + l15] = accg[mt][reg] + opbv;
  } else {
    int t4 = (wave - 4)*64 + lane;
    for (int i = t4; i < 4096; i += 768){
      int p = i >> 11, rem = i & 2047, r = rem >> 6, gg = rem & 63;
      short8 v = *(const short8*)((p ? gam : gah) + r*512 + ((gg ^ (r & 7)) << 3));
      unsigned short* dst = (p ? fl : fh) + (size_t)(r0 + r)*512 + gg*8;
      *(short8*)dst = v;
    }
  }
  __syncthreads();

  {
    for (int rr = 0; rr < 2; rr++){
      int r = wave*2 + rr, row = r0 + r;
      float l = lg[r][lane];
      float mx = l;
      #pragma unroll
      for (int o = 32; o; o >>= 1) mx = fmaxf(mx, __shfl_xor(mx, o, 64));
      float p = expf(l - mx);
      float s = wave_sum64(p);
      p /= s;
      float pv = p;
      for (int j = 0; j < 3; j++){
        float v = pv; int idx = lane;
        #pragma unroll
        for (int o = 32; o; o >>= 1){
          float ov = __shfl_xor(v, o, 64);
          int   oi = __shfl_xor(idx, o, 64);
          if (ov > v || (ov == v && oi < idx)){ v = ov; idx = oi; }
        }
        if (lane == 0){
          dout[(size_t)row*3 + j]                = v;
          dout[(size_t)Bv*3 + (size_t)row*3 + j] = (float)idx;
        }
        if (v >= CONFv){
          if (lane == 0){
            int pos = atomicAdd(&cnt[idx], 1);
            list[idx*Bv + pos] = (row << 2) | j;
          }
        } else {
          if (lane < 16) dout[(size_t)Bv*6 + (size_t)row*48 + j*16 + lane] = 0.f;
        }
        if (lane == idx) pv = -1.0f;
      }
    }
  }
}

// ---------------- kernel 3: expert MLP, M=64 tile, direct fp32 weights ----
// (exact R5 body — best measured config)
__global__ __launch_bounds__(1024) void k_expert(const unsigned short* __restrict__ fh,
    const unsigned short* __restrict__ fl,
    const float* __restrict__ pw1, const float* __restrict__ b1,
    const float* __restrict__ g,  const float* __restrict__ beta,
    const unsigned short* __restrict__ p2, const float* __restrict__ b2,
    const int* __restrict__ cnt,  const int* __restrict__ list,
    float* __restrict__ dout)
{
  __shared__ unsigned short xbuf[65536];             // xh [64][512] | xl [64][512]
  unsigned short* xh = xbuf;
  unsigned short* xl = xbuf + 32768;
  unsigned short* zp = xbuf;                         // overlay [64][528] hi/lo
  __shared__ float ps[64][16];
  __shared__ float pq[64][16];
  __shared__ float mi[64][2];
  __shared__ int sdesc[3];

  const int tid = threadIdx.x;
  const int wave = tid >> 6, lane = tid & 63;
  const int lquad = lane >> 4, l15 = lane & 15;

  if (wave == 0){
    int c  = cnt[lane];
    int tl = (c + 63) >> 6;
    int incl = tl;
    #pragma unroll
    for (int o = 1; o < 64; o <<= 1){
      int v = __shfl_up(incl, o, 64);
      if (lane >= o) incl += v;
    }
    int total = __shfl(incl, 63, 64);
    int G   = (total + 7) >> 3;
    int grp = blockIdx.x & 7, rr = blockIdx.x >> 3;
    int lgc = grp*G + rr;
    int ok  = (G > 0) && (rr < G) && (lgc < total);
    unsigned long long bm = __ballot(ok && (incl > lgc));
    if (lane == 0){
      if (!ok || bm == 0ull){ sdesc[0] = -1; }
      else {
        int e = __ffsll((long long)bm) - 1;
        sdesc[0] = e; sdesc[1] = lgc; sdesc[2] = 0;
      }
    }
    if (bm != 0ull && ok){
      int e = __ffsll((long long)bm) - 1;
      int excl = __shfl(incl - tl, e, 64);
      int ne   = __shfl(c, e, 64);
      if (lane == 0){ sdesc[1] = lgc - excl; sdesc[2] = ne; }
    }
  }
  __syncthreads();
  const int e = sdesc[0];
  if (e < 0) return;
  const int t = sdesc[1];
  const int n = sdesc[2];
  const int base = t * 64;
  const int m = min(64, n - base);
  const int* lrow = list + e*Bv + base;

  // ---- stage feats hi/lo planes (64 rows) -> swizzled LDS
  for (int i = tid; i < 8192; i += 1024){
    int p = i >> 12, rem = i & 4095, r = rem >> 6, gg = rem & 63;
    int ev = lrow[(r < m) ? r : 0];
    int row = ev >> 2;
    const unsigned short* src = (p ? fl : fh) + (size_t)row*512 + gg*8;
    short8 v = *(const short8*)src;
    unsigned short* dst = (p ? xl : xh) + r*512 + ((gg ^ (r & 7)) << 3);
    *(short8*)dst = v;
  }
  __syncthreads();

  // ---- GEMM1: M=64, N=256, K=512; wave w owns ntile w (16 cols), 4 mtiles
  const float* bw = pw1 + (size_t)e*131072 + wave*16 + l15;
  f32x4 acc[4];
  #pragma unroll
  for (int mt = 0; mt < 4; mt++) acc[mt] = (f32x4){0.f,0.f,0.f,0.f};

  for (int kt = 0; kt < 16; kt++){
    const float* bk = bw + (size_t)(kt*32 + lquad*8)*256;
    float wv[8];
    #pragma unroll
    for (int j = 0; j < 8; j++) wv[j] = bk[(size_t)j*256];
    short8 bh, bl;
    #pragma unroll
    for (int j = 0; j < 8; j++){
      unsigned u = __float_as_uint(wv[j]);
      float r2 = wv[j] - __uint_as_float(u & 0xffff0000u);
      bh[j] = (short)(u >> 16);
      bl[j] = (short)(__float_as_uint(r2) >> 16);
    }
    int gk = kt*4 + lquad;
    #pragma unroll
    for (int mt = 0; mt < 4; mt++){
      int r = mt*16 + l15;
      int off = r*512 + ((gk ^ (r & 7)) << 3);
      short8 ah = *(const short8*)(xh + off);
      short8 al = *(const short8*)(xl + off);
      acc[mt] = mfma3(ah, al, bh, bl, acc[mt]);
    }
  }

  // ---- bias + LN partials (each wave: 16-col partial for its ntile)
  float bb, gv, bv;
  {
    int col = wave*16 + l15;
    bb = b1[e*256 + col];
    gv = g[e*256 + col];
    bv = beta[e*256 + col];
  }
  #pragma unroll
  for (int mt = 0; mt < 4; mt++)
    #pragma unroll
    for (int reg = 0; reg < 4; reg++){
      float z = acc[mt][reg] + bb;
      float s = z, q = z*z;
      #pragma unroll
      for (int o = 1; o < 16; o <<= 1){ s += __shfl_xor(s, o, 64); q += __shfl_xor(q, o, 64); }
      int row = mt*16 + lquad*4 + reg;
      if (l15 == 0){ ps[row][wave] = s; pq[row][wave] = q; }
    }
  __syncthreads();   // all xh/xl reads done -> zp overlay safe
  if (tid < 64){
    int row = tid;
    float s = 0.f, q = 0.f;
    #pragma unroll
    for (int c4 = 0; c4 < 4; c4++){
      float4 sv = *(const float4*)&ps[row][c4*4];
      float4 qv = *(const float4*)&pq[row][c4*4];
      s += sv.x + sv.y + sv.z + sv.w;
      q += qv.x + qv.y + qv.z + qv.w;
    }
    float mean = s * (1.0f/256.0f);
    float var  = q * (1.0f/256.0f) - mean*mean;
    mi[row][0] = mean;
    mi[row][1] = 1.0f / sqrtf(var + EPSv);
  }
  __syncthreads();

  // ---- LN finalize + ReLU -> zp hi/lo planes (row stride 528)
  #pragma unroll
  for (int mt = 0; mt < 4; mt++)
    #pragma unroll
    for (int reg = 0; reg < 4; reg++){
      int row = mt*16 + lquad*4 + reg;
      float2 mv = *(const float2*)mi[row];
      int col = wave*16 + l15;
      float z = acc[mt][reg] + bb;
      float y = fmaxf((z - mv.x)*mv.y*gv + bv, 0.f);
      short hh, mm2;
      split2f(y, hh, mm2);
      zp[row*528 + col]       = (unsigned short)hh;
      zp[row*528 + 264 + col] = (unsigned short)mm2;
    }
  __syncthreads();

  // ---- GEMM2: 64x16, K=256, 3-pass; waves 0..3 handle 16 rows each
  if (wave < 4){
    const unsigned short* p2e = p2 + (size_t)e * 8192;
    f32x4 acc2 = (f32x4){0.f,0.f,0.f,0.f};
    for (int kt2 = 0; kt2 < 8; kt2++){
      const unsigned short* zb = zp + (wave*16 + l15)*528 + kt2*32 + lquad*8;
      short8 ahh = *(const short8*)zb;
      short8 all2 = *(const short8*)(zb + 264);
      const unsigned short* bp = p2e + ((kt2*64 + lane) << 3);
      short8 bh = *(const short8*)bp;
      short8 bl = *(const short8*)(bp + 4096);
      acc2 = mfma3(ahh, all2, bh, bl, acc2);
    }
    float b2v = b2[e*16 + l15];
    #pragma unroll
    for (int reg = 0; reg < 4; reg++){
      int rl = wave*16 + lquad*4 + reg;
      if (rl < m){
        int ev = lrow[rl];
        int row = ev >> 2, j = ev & 3;
        dout[(size_t)Bv*6 + (size_t)row*48 + j*16 + l15] = acc2[reg] + b2v;
      }
    }
  }
}

extern "C" void kernel_launch(void* const* d_in, const int* in_sizes, int n_in,
                              void* d_out, int out_size, void* d_ws, size_t ws_size,
                              hipStream_t stream)
{
  const float* X   = (const float*)d_in[0];
  const float* w1  = (const float*)d_in[1];
  const float* b1  = (const float*)d_in[2];
  const float* g1  = (const float*)d_in[3];
  const float* be1 = (const float*)d_in[4];
  const float* w2  = (const float*)d_in[5];
  const float* b2  = (const float*)d_in[6];
  const float* g2  = (const float*)d_in[7];
  const float* be2 = (const float*)d_in[8];
  const float* opw = (const float*)d_in[9];
  const float* opb = (const float*)d_in[10];
  const float* pw1 = (const float*)d_in[11];
  const float* pb1 = (const float*)d_in[12];
  const float* pg  = (const float*)d_in[13];
  const float* pbe = (const float*)d_in[14];
  const float* pw2 = (const float*)d_in[15];
  const float* pb2 = (const float*)d_in[16];
  float* out = (float*)d_out;
  char*  ws  = (char*)d_ws;

  unsigned short* p2E    = (unsigned short*)(ws + (size_t)32*MB);
  unsigned short* fh     = (unsigned short*)(ws + (size_t)36*MB);
  unsigned short* fl     = (unsigned short*)(ws + (size_t)44*MB);
  int*            list   = (int*)(ws + (size_t)52*MB);
  int*            cnt    = (int*)(ws + (size_t)54*MB);

  k_pre   <<<129, 256, 0, stream>>>(pw2, p2E, cnt);
  k_fused <<<256, 1024, 65536, stream>>>(X, w1, b1, g1, be1,
                                         w2, b2, g2, be2, opw, opb,
                                         fh, fl, out, cnt, list);
  k_expert<<<448, 1024, 0, stream>>>(fh, fl, pw1, pb1, pg, pbe, p2E, pb2,
                                     cnt, list, out);
}

// Round 11
// 163.635 us; speedup vs baseline: 1.0612x; 1.0364x over previous
//
#include <hip/hip_runtime.h>
#include <math.h>

#define Bv   8192
#define EPSv 1e-5f
#define CONFv 0.1f
#define MB (1024*1024)

typedef __attribute__((ext_vector_type(8))) short short8;
typedef __attribute__((ext_vector_type(4))) float f32x4;

__device__ __forceinline__ float wave_sum64(float v){
  #pragma unroll
  for (int o = 32; o; o >>= 1) v += __shfl_xor(v, o, 64);
  return v;
}

__device__ __forceinline__ void split3f(float x, short &h, short &m, short &l){
  unsigned u = __float_as_uint(x);
  h = (short)(u >> 16);
  float r1 = x - __uint_as_float(u & 0xffff0000u);
  unsigned u1 = __float_as_uint(r1);
  m = (short)(u1 >> 16);
  float r2 = r1 - __uint_as_float(u1 & 0xffff0000u);
  l = (short)(__float_as_uint(r2) >> 16);
}

__device__ __forceinline__ void split2f(float x, short &h, short &m){
  unsigned u = __float_as_uint(x);
  h = (short)(u >> 16);
  float r1 = x - __uint_as_float(u & 0xffff0000u);
  m = (short)(__float_as_uint(r1) >> 16);
}

// 5-pass: A 2-plane (h,m) x B 3-plane. Error ~2^-24-class.
__device__ __forceinline__ f32x4 mfma5(short8 ah, short8 am,
                                       short8 bh, short8 bm, short8 bl, f32x4 c){
  c = __builtin_amdgcn_mfma_f32_16x16x32_bf16(am, bm, c, 0, 0, 0);
  c = __builtin_amdgcn_mfma_f32_16x16x32_bf16(ah, bl, c, 0, 0, 0);
  c = __builtin_amdgcn_mfma_f32_16x16x32_bf16(am, bh, c, 0, 0, 0);
  c = __builtin_amdgcn_mfma_f32_16x16x32_bf16(ah, bm, c, 0, 0, 0);
  c = __builtin_amdgcn_mfma_f32_16x16x32_bf16(ah, bh, c, 0, 0, 0);
  return c;
}

__device__ __forceinline__ f32x4 mfma3(short8 ah, short8 al,
                                       short8 bh, short8 bl, f32x4 c){
  c = __builtin_amdgcn_mfma_f32_16x16x32_bf16(al, bh, c, 0, 0, 0);
  c = __builtin_amdgcn_mfma_f32_16x16x32_bf16(ah, bl, c, 0, 0, 0);
  c = __builtin_amdgcn_mfma_f32_16x16x32_bf16(ah, bh, c, 0, 0, 0);
  return c;
}

// ---------------- kernel 1: rp-path packing + p2E pack + cnt zero ---------
// (exact R5 — best measured config, 164.7us total)
__global__ __launch_bounds__(256) void k_pre(
    const float* __restrict__ w1, const float* __restrict__ w2,
    const float* __restrict__ opw, const float* __restrict__ pw2,
    unsigned short* __restrict__ w1p, unsigned short* __restrict__ w2p,
    unsigned short* __restrict__ opwp, unsigned short* __restrict__ p2,
    int* __restrict__ cnt)
{
  int bid = blockIdx.x;
  if (bid < 128){
    int gid = bid*256 + threadIdx.x;                  // 32768, K=128, N=256
    int k = gid >> 8, n = gid & 255;
    short h, m, l;
    split3f(w1[gid], h, m, l);
    int idx = (((n >> 4)*4 + (k >> 5))*64 + (((k >> 3) & 3)*16 + (n & 15)))*8 + (k & 7);
    w1p[idx]             = (unsigned short)h;
    w1p[32768 + idx]     = (unsigned short)m;
    w1p[2*32768 + idx]   = (unsigned short)l;
  } else if (bid < 640){
    int gid = (bid - 128)*256 + threadIdx.x;          // 131072, K=256, N=512
    int k = gid >> 9, n = gid & 511;
    short h, m, l;
    split3f(w2[gid], h, m, l);
    int idx = (((n >> 4)*8 + (k >> 5))*64 + (((k >> 3) & 3)*16 + (n & 15)))*8 + (k & 7);
    w2p[idx]             = (unsigned short)h;
    w2p[131072 + idx]    = (unsigned short)m;
    w2p[2*131072 + idx]  = (unsigned short)l;
  } else if (bid < 768){
    int gid = (bid - 640)*256 + threadIdx.x;          // 32768, K=512, N=64
    int k = gid >> 6, n = gid & 63;
    short h, m, l;
    split3f(opw[gid], h, m, l);
    int idx = (((n >> 4)*16 + (k >> 5))*64 + (((k >> 3) & 3)*16 + (n & 15)))*8 + (k & 7);
    opwp[idx]            = (unsigned short)h;
    opwp[32768 + idx]    = (unsigned short)m;
    opwp[2*32768 + idx]  = (unsigned short)l;
  } else if (bid < 896){
    int t = (bid - 768)*256 + threadIdx.x;            // [0, 32768)  pe_w2 pack
    int e = t >> 9, rem = t & 511, kg = rem >> 4, n = rem & 15;
    const float* src = pw2 + (size_t)e*4096 + (size_t)(kg*8)*16 + n;
    short8 h, l;
    #pragma unroll
    for (int j = 0; j < 8; j++){
      float w = src[(size_t)j*16];
      unsigned u = __float_as_uint(w);
      float r2 = w - __uint_as_float(u & 0xffff0000u);
      h[j] = (short)(u >> 16);
      l[j] = (short)(__float_as_uint(r2) >> 16);
    }
    int idx8 = (((kg >> 2)*64) + (kg & 3)*16 + n) << 3;
    unsigned short* ep = p2 + (size_t)e * 8192;
    *(short8*)(ep + idx8)        = h;
    *(short8*)(ep + 4096 + idx8) = l;
  } else {
    if (threadIdx.x < 64) cnt[threadIdx.x] = 0;
  }
}

// ---------------- kernel 2: fused rp1->rp2->gate, 256 blocks (pure) -------
__global__ __launch_bounds__(1024) void k_fused(const float* __restrict__ X,
    const unsigned short* __restrict__ w1p, const float* __restrict__ b1,
    const float* __restrict__ g1, const float* __restrict__ be1,
    const unsigned short* __restrict__ w2p, const float* __restrict__ b2,
    const float* __restrict__ g2, const float* __restrict__ be2,
    const unsigned short* __restrict__ opwp, const float* __restrict__ opb,
    unsigned short* __restrict__ fh, unsigned short* __restrict__ fl,
    float* __restrict__ dout, int* __restrict__ cnt, int* __restrict__ list)
{
  extern __shared__ unsigned char smem[];
  unsigned short* xh  = (unsigned short*)smem;          // [32][128]
  unsigned short* xm  = xh + 4096;
  unsigned short* hbh = xh + 8192;                      // [32][256]
  unsigned short* hbm = xh + 16384;
  unsigned short* gah = xh;                             // [32][512] overlay
  unsigned short* gam = xh + 16384;
  __shared__ float ps[32][20];
  __shared__ float pq[32][20];
  __shared__ float mi[32][2];
  __shared__ float lg[32][64];

  const int tid = threadIdx.x;
  const int r0  = blockIdx.x * 32;
  const int wave = tid >> 6, lane = tid & 63, lquad = lane >> 4, l15 = lane & 15;

  {
    int r = tid >> 5, c4 = tid & 31;
    float4 v = ((const float4*)X)[(size_t)(r0+r)*32 + c4];
    unsigned u0 = __float_as_uint(v.x), u1 = __float_as_uint(v.y);
    unsigned u2 = __float_as_uint(v.z), u3 = __float_as_uint(v.w);
    float m0 = v.x - __uint_as_float(u0 & 0xffff0000u);
    float m1 = v.y - __uint_as_float(u1 & 0xffff0000u);
    float m2 = v.z - __uint_as_float(u2 & 0xffff0000u);
    float m3 = v.w - __uint_as_float(u3 & 0xffff0000u);
    unsigned hp0 = (u0 >> 16) | (u1 & 0xffff0000u);
    unsigned hp1 = (u2 >> 16) | (u3 & 0xffff0000u);
    unsigned mp0 = (__float_as_uint(m0) >> 16) | (__float_as_uint(m1) & 0xffff0000u);
    unsigned mp1 = (__float_as_uint(m2) >> 16) | (__float_as_uint(m3) & 0xffff0000u);
    int gk = c4 >> 1, half = c4 & 1;
    int off = r*128 + ((gk ^ (r & 7)) << 3) + half*4;
    ((unsigned*)(xh + off))[0] = hp0;
    ((unsigned*)(xh + off))[1] = hp1;
    ((unsigned*)(xm + off))[0] = mp0;
    ((unsigned*)(xm + off))[1] = mp1;
  }
  __syncthreads();

  float bcol1, gcol1, becol1;
  {
    int col = wave*16 + l15;
    bcol1 = b1[col]; gcol1 = g1[col]; becol1 = be1[col];
  }
  {
    f32x4 acc[2];
    acc[0] = (f32x4){0.f,0.f,0.f,0.f};
    acc[1] = (f32x4){0.f,0.f,0.f,0.f};
    const int pstride = 32768;
    for (int ks4 = 0; ks4 < 4; ks4++){
      const unsigned short* bp = w1p + (((wave*4 + ks4)*64 + lane) << 3);
      short8 bh = *(const short8*)bp;
      short8 bm = *(const short8*)(bp + pstride);
      short8 bl = *(const short8*)(bp + 2*pstride);
      #pragma unroll
      for (int mt = 0; mt < 2; mt++){
        int r = mt*16 + l15;
        int off = r*128 + (((ks4*4 + lquad) ^ (r & 7)) << 3);
        short8 ah = *(const short8*)(xh + off);
        short8 am = *(const short8*)(xm + off);
        acc[mt] = mfma5(ah, am, bh, bm, bl, acc[mt]);
      }
    }
    #pragma unroll
    for (int mt = 0; mt < 2; mt++)
      #pragma unroll
      for (int reg = 0; reg < 4; reg++){
        float z = acc[mt][reg] + bcol1;
        float s = z, q = z*z;
        #pragma unroll
        for (int o = 1; o < 16; o <<= 1){ s += __shfl_xor(s, o, 64); q += __shfl_xor(q, o, 64); }
        int row = mt*16 + lquad*4 + reg;
        if (l15 == 0){ ps[row][wave] = s; pq[row][wave] = q; }
      }
    __syncthreads();
    if (tid < 32){
      int row = tid;
      float4 s0 = *(const float4*)&ps[row][0],  s1 = *(const float4*)&ps[row][4];
      float4 s2 = *(const float4*)&ps[row][8],  s3 = *(const float4*)&ps[row][12];
      float4 q0 = *(const float4*)&pq[row][0],  q1 = *(const float4*)&pq[row][4];
      float4 q2 = *(const float4*)&pq[row][8],  q3 = *(const float4*)&pq[row][12];
      float s = s0.x; s += s0.y; s += s0.z; s += s0.w;
      s += s1.x; s += s1.y; s += s1.z; s += s1.w;
      s += s2.x; s += s2.y; s += s2.z; s += s2.w;
      s += s3.x; s += s3.y; s += s3.z; s += s3.w;
      float q = q0.x; q += q0.y; q += q0.z; q += q0.w;
      q += q1.x; q += q1.y; q += q1.z; q += q1.w;
      q += q2.x; q += q2.y; q += q2.z; q += q2.w;
      q += q3.x; q += q3.y; q += q3.z; q += q3.w;
      float mean = s * (1.0f/256.0f);
      float var  = q * (1.0f/256.0f) - mean*mean;
      mi[row][0] = mean;
      mi[row][1] = 1.0f / sqrtf(var + EPSv);
    }
    __syncthreads();
    #pragma unroll
    for (int mt = 0; mt < 2; mt++)
      #pragma unroll
      for (int reg = 0; reg < 4; reg++){
        int row = mt*16 + lquad*4 + reg;
        float2 mv = *(const float2*)mi[row];
        int col = wave*16 + l15;
        float z = acc[mt][reg] + bcol1;
        float y = fmaxf((z - mv.x)*mv.y*gcol1 + becol1, 0.f);
        short hh, mm2;
        split2f(y, hh, mm2);
        int gg = col >> 3, c7 = col & 7;
        int adr = row*256 + ((gg ^ (row & 7)) << 3) + c7;
        hbh[adr] = (unsigned short)hh;
        hbm[adr] = (unsigned short)mm2;
      }
  }
  __syncthreads();

  f32x4 acc2[2][2];
  #pragma unroll
  for (int mt = 0; mt < 2; mt++)
    #pragma unroll
    for (int nt = 0; nt < 2; nt++) acc2[mt][nt] = (f32x4){0.f,0.f,0.f,0.f};
  {
    const int pstride = 131072;
    for (int ks4 = 0; ks4 < 8; ks4++){
      short8 ah[2], am[2];
      #pragma unroll
      for (int mt = 0; mt < 2; mt++){
        int r = mt*16 + l15;
        int off = r*256 + (((ks4*4 + lquad) ^ (r & 7)) << 3);
        ah[mt] = *(const short8*)(hbh + off);
        am[mt] = *(const short8*)(hbm + off);
      }
      #pragma unroll
      for (int nt = 0; nt < 2; nt++){
        int ntg = wave*2 + nt;
        const unsigned short* bp = w2p + (((ntg*8 + ks4)*64 + lane) << 3);
        short8 bh = *(const short8*)bp;
        short8 bm = *(const short8*)(bp + pstride);
        short8 bl = *(const short8*)(bp + 2*pstride);
        #pragma unroll
        for (int mt = 0; mt < 2; mt++)
          acc2[mt][nt] = mfma5(ah[mt], am[mt], bh, bm, bl, acc2[mt][nt]);
      }
    }
  }

  float bcol[2], gcol[2], becol[2];
  #pragma unroll
  for (int nt = 0; nt < 2; nt++){
    int col = (wave*2 + nt)*16 + l15;
    bcol[nt] = b2[col]; gcol[nt] = g2[col]; becol[nt] = be2[col];
  }
  #pragma unroll
  for (int mt = 0; mt < 2; mt++)
    #pragma unroll
    for (int reg = 0; reg < 4; reg++){
      float s = 0.f, q = 0.f;
      #pragma unroll
      for (int nt = 0; nt < 2; nt++){
        float z = acc2[mt][nt][reg] + bcol[nt];
        s += z; q += z*z;
      }
      #pragma unroll
      for (int o = 1; o < 16; o <<= 1){ s += __shfl_xor(s, o, 64); q += __shfl_xor(q, o, 64); }
      int row = mt*16 + lquad*4 + reg;
      if (l15 == 0){ ps[row][wave] = s; pq[row][wave] = q; }
    }
  __syncthreads();
  if (tid < 32){
    int row = tid;
    float4 s0 = *(const float4*)&ps[row][0],  s1 = *(const float4*)&ps[row][4];
    float4 s2 = *(const float4*)&ps[row][8],  s3 = *(const float4*)&ps[row][12];
    float4 q0 = *(const float4*)&pq[row][0],  q1 = *(const float4*)&pq[row][4];
    float4 q2 = *(const float4*)&pq[row][8],  q3 = *(const float4*)&pq[row][12];
    float s = s0.x; s += s0.y; s += s0.z; s += s0.w;
    s += s1.x; s += s1.y; s += s1.z; s += s1.w;
    s += s2.x; s += s2.y; s += s2.z; s += s2.w;
    s += s3.x; s += s3.y; s += s3.z; s += s3.w;
    float q = q0.x; q += q0.y; q += q0.z; q += q0.w;
    q += q1.x; q += q1.y; q += q1.z; q += q1.w;
    q += q2.x; q += q2.y; q += q2.z; q += q2.w;
    q += q3.x; q += q3.y; q += q3.z; q += q3.w;
    float mean = s * (1.0f/512.0f);
    float var  = q * (1.0f/512.0f) - mean*mean;
    mi[row][0] = mean;
    mi[row][1] = 1.0f / sqrtf(var + EPSv);
  }
  __syncthreads();

  #pragma unroll
  for (int mt = 0; mt < 2; mt++)
    #pragma unroll
    for (int reg = 0; reg < 4; reg++){
      int row = mt*16 + lquad*4 + reg;
      float2 mv = *(const float2*)mi[row];
      #pragma unroll
      for (int nt = 0; nt < 2; nt++){
        int col = (wave*2 + nt)*16 + l15;
        float z = acc2[mt][nt][reg] + bcol[nt];
        float y = fmaxf((z - mv.x)*mv.y*gcol[nt] + becol[nt], 0.f);
        short hh, mm2;
        split2f(y, hh, mm2);
        int gg = col >> 3, c7 = col & 7;
        int adr = row*512 + ((gg ^ (row & 7)) << 3) + c7;
        gah[adr] = (unsigned short)hh;
        gam[adr] = (unsigned short)mm2;
      }
    }
  __syncthreads();

  if (wave < 4){
    f32x4 accg[2];
    accg[0] = (f32x4){0.f,0.f,0.f,0.f};
    accg[1] = (f32x4){0.f,0.f,0.f,0.f};
    for (int kt = 0; kt < 16; kt++){
      const unsigned short* bp = opwp + (((wave*16 + kt)*64 + lane) << 3);
      short8 bh = *(const short8*)bp;
      short8 bm = *(const short8*)(bp + 32768);
      short8 bl = *(const short8*)(bp + 65536);
      #pragma unroll
      for (int mt = 0; mt < 2; mt++){
        int r = mt*16 + l15;
        int off = r*512 + (((kt*4 + lquad) ^ (r & 7)) << 3);
        short8 ah = *(const short8*)(gah + off);
        short8 am = *(const short8*)(gam + off);
        accg[mt] = mfma5(ah, am, bh, bm, bl, accg[mt]);
      }
    }
    float opbv = opb[wave*16 + l15];
    #pragma unroll
    for (int mt = 0; mt < 2; mt++)
      #pragma unroll
      for (int reg = 0; reg < 4; reg++)
        lg[mt*16 + lquad*4 + reg][wave*16 + l15] = accg[mt][reg] + opbv;
  } else {
    int t4 = (wave - 4)*64 + lane;
    for (int i = t4; i < 4096; i += 768){
      int p = i >> 11, rem = i & 2047, r = rem >> 6, gg = rem & 63;
      short8 v = *(const short8*)((p ? gam : gah) + r*512 + ((gg ^ (r & 7)) << 3));
      unsigned short* dst = (p ? fl : fh) + (size_t)(r0 + r)*512 + gg*8;
      *(short8*)dst = v;
    }
  }
  __syncthreads();

  {
    for (int rr = 0; rr < 2; rr++){
      int r = wave*2 + rr, row = r0 + r;
      float l = lg[r][lane];
      float mx = l;
      #pragma unroll
      for (int o = 32; o; o >>= 1) mx = fmaxf(mx, __shfl_xor(mx, o, 64));
      float p = expf(l - mx);
      float s = wave_sum64(p);
      p /= s;
      float pv = p;
      for (int j = 0; j < 3; j++){
        float v = pv; int idx = lane;
        #pragma unroll
        for (int o = 32; o; o >>= 1){
          float ov = __shfl_xor(v, o, 64);
          int   oi = __shfl_xor(idx, o, 64);
          if (ov > v || (ov == v && oi < idx)){ v = ov; idx = oi; }
        }
        if (lane == 0){
          dout[(size_t)row*3 + j]                = v;
          dout[(size_t)Bv*3 + (size_t)row*3 + j] = (float)idx;
        }
        if (v >= CONFv){
          if (lane == 0){
            int pos = atomicAdd(&cnt[idx], 1);
            list[idx*Bv + pos] = (row << 2) | j;
          }
        } else {
          if (lane < 16) dout[(size_t)Bv*6 + (size_t)row*48 + j*16 + lane] = 0.f;
        }
        if (lane == idx) pv = -1.0f;
      }
    }
  }
}

// ---------------- kernel 3: expert MLP, M=64 tile, direct fp32 weights ----
// (exact R5 body — best measured config)
__global__ __launch_bounds__(1024) void k_expert(const unsigned short* __restrict__ fh,
    const unsigned short* __restrict__ fl,
    const float* __restrict__ pw1, const float* __restrict__ b1,
    const float* __restrict__ g,  const float* __restrict__ beta,
    const unsigned short* __restrict__ p2, const float* __restrict__ b2,
    const int* __restrict__ cnt,  const int* __restrict__ list,
    float* __restrict__ dout)
{
  __shared__ unsigned short xbuf[65536];             // xh [64][512] | xl [64][512]
  unsigned short* xh = xbuf;
  unsigned short* xl = xbuf + 32768;
  unsigned short* zp = xbuf;                         // overlay [64][528] hi/lo
  __shared__ float ps[64][16];
  __shared__ float pq[64][16];
  __shared__ float mi[64][2];
  __shared__ int sdesc[3];

  const int tid = threadIdx.x;
  const int wave = tid >> 6, lane = tid & 63;
  const int lquad = lane >> 4, l15 = lane & 15;

  if (wave == 0){
    int c  = cnt[lane];
    int tl = (c + 63) >> 6;
    int incl = tl;
    #pragma unroll
    for (int o = 1; o < 64; o <<= 1){
      int v = __shfl_up(incl, o, 64);
      if (lane >= o) incl += v;
    }
    int total = __shfl(incl, 63, 64);
    int G   = (total + 7) >> 3;
    int grp = blockIdx.x & 7, rr = blockIdx.x >> 3;
    int lgc = grp*G + rr;
    int ok  = (G > 0) && (rr < G) && (lgc < total);
    unsigned long long bm = __ballot(ok && (incl > lgc));
    if (lane == 0){
      if (!ok || bm == 0ull){ sdesc[0] = -1; }
      else {
        int e = __ffsll((long long)bm) - 1;
        sdesc[0] = e; sdesc[1] = lgc; sdesc[2] = 0;
      }
    }
    if (bm != 0ull && ok){
      int e = __ffsll((long long)bm) - 1;
      int excl = __shfl(incl - tl, e, 64);
      int ne   = __shfl(c, e, 64);
      if (lane == 0){ sdesc[1] = lgc - excl; sdesc[2] = ne; }
    }
  }
  __syncthreads();
  const int e = sdesc[0];
  if (e < 0) return;
  const int t = sdesc[1];
  const int n = sdesc[2];
  const int base = t * 64;
  const int m = min(64, n - base);
  const int* lrow = list + e*Bv + base;

  // ---- stage feats hi/lo planes (64 rows) -> swizzled LDS
  for (int i = tid; i < 8192; i += 1024){
    int p = i >> 12, rem = i & 4095, r = rem >> 6, gg = rem & 63;
    int ev = lrow[(r < m) ? r : 0];
    int row = ev >> 2;
    const unsigned short* src = (p ? fl : fh) + (size_t)row*512 + gg*8;
    short8 v = *(const short8*)src;
    unsigned short* dst = (p ? xl : xh) + r*512 + ((gg ^ (r & 7)) << 3);
    *(short8*)dst = v;
  }
  __syncthreads();

  // ---- GEMM1: M=64, N=256, K=512; wave w owns ntile w (16 cols), 4 mtiles
  const float* bw = pw1 + (size_t)e*131072 + wave*16 + l15;
  f32x4 acc[4];
  #pragma unroll
  for (int mt = 0; mt < 4; mt++) acc[mt] = (f32x4){0.f,0.f,0.f,0.f};

  for (int kt = 0; kt < 16; kt++){
    const float* bk = bw + (size_t)(kt*32 + lquad*8)*256;
    float wv[8];
    #pragma unroll
    for (int j = 0; j < 8; j++) wv[j] = bk[(size_t)j*256];
    short8 bh, bl;
    #pragma unroll
    for (int j = 0; j < 8; j++){
      unsigned u = __float_as_uint(wv[j]);
      float r2 = wv[j] - __uint_as_float(u & 0xffff0000u);
      bh[j] = (short)(u >> 16);
      bl[j] = (short)(__float_as_uint(r2) >> 16);
    }
    int gk = kt*4 + lquad;
    #pragma unroll
    for (int mt = 0; mt < 4; mt++){
      int r = mt*16 + l15;
      int off = r*512 + ((gk ^ (r & 7)) << 3);
      short8 ah = *(const short8*)(xh + off);
      short8 al = *(const short8*)(xl + off);
      acc[mt] = mfma3(ah, al, bh, bl, acc[mt]);
    }
  }

  // ---- bias + LN partials (each wave: 16-col partial for its ntile)
  float bb, gv, bv;
  {
    int col = wave*16 + l15;
    bb = b1[e*256 + col];
    gv = g[e*256 + col];
    bv = beta[e*256 + col];
  }
  #pragma unroll
  for (int mt = 0; mt < 4; mt++)
    #pragma unroll
    for (int reg = 0; reg < 4; reg++){
      float z = acc[mt][reg] + bb;
      float s = z, q = z*z;
      #pragma unroll
      for (int o = 1; o < 16; o <<= 1){ s += __shfl_xor(s, o, 64); q += __shfl_xor(q, o, 64); }
      int row = mt*16 + lquad*4 + reg;
      if (l15 == 0){ ps[row][wave] = s; pq[row][wave] = q; }
    }
  __syncthreads();   // all xh/xl reads done -> zp overlay safe
  if (tid < 64){
    int row = tid;
    float s = 0.f, q = 0.f;
    #pragma unroll
    for (int c4 = 0; c4 < 4; c4++){
      float4 sv = *(const float4*)&ps[row][c4*4];
      float4 qv = *(const float4*)&pq[row][c4*4];
      s += sv.x + sv.y + sv.z + sv.w;
      q += qv.x + qv.y + qv.z + qv.w;
    }
    float mean = s * (1.0f/256.0f);
    float var  = q * (1.0f/256.0f) - mean*mean;
    mi[row][0] = mean;
    mi[row][1] = 1.0f / sqrtf(var + EPSv);
  }
  __syncthreads();

  // ---- LN finalize + ReLU -> zp hi/lo planes (row stride 528)
  #pragma unroll
  for (int mt = 0; mt < 4; mt++)
    #pragma unroll
    for (int reg = 0; reg < 4; reg++){
      int row = mt*16 + lquad*4 + reg;
      float2 mv = *(const float2*)mi[row];
      int col = wave*16 + l15;
      float z = acc[mt][reg] + bb;
      float y = fmaxf((z - mv.x)*mv.y*gv + bv, 0.f);
      short hh, mm2;
      split2f(y, hh, mm2);
      zp[row*528 + col]       = (unsigned short)hh;
      zp[row*528 + 264 + col] = (unsigned short)mm2;
    }
  __syncthreads();

  // ---- GEMM2: 64x16, K=256, 3-pass; waves 0..3 handle 16 rows each
  if (wave < 4){
    const unsigned short* p2e = p2 + (size_t)e * 8192;
    f32x4 acc2 = (f32x4){0.f,0.f,0.f,0.f};
    for (int kt2 = 0; kt2 < 8; kt2++){
      const unsigned short* zb = zp + (wave*16 + l15)*528 + kt2*32 + lquad*8;
      short8 ahh = *(const short8*)zb;
      short8 all2 = *(const short8*)(zb + 264);
      const unsigned short* bp = p2e + ((kt2*64 + lane) << 3);
      short8 bh = *(const short8*)bp;
      short8 bl = *(const short8*)(bp + 4096);
      acc2 = mfma3(ahh, all2, bh, bl, acc2);
    }
    float b2v = b2[e*16 + l15];
    #pragma unroll
    for (int reg = 0; reg < 4; reg++){
      int rl = wave*16 + lquad*4 + reg;
      if (rl < m){
        int ev = lrow[rl];
        int row = ev >> 2, j = ev & 3;
        dout[(size_t)Bv*6 + (size_t)row*48 + j*16 + l15] = acc2[reg] + b2v;
      }
    }
  }
}

extern "C" void kernel_launch(void* const* d_in, const int* in_sizes, int n_in,
                              void* d_out, int out_size, void* d_ws, size_t ws_size,
                              hipStream_t stream)
{
  const float* X   = (const float*)d_in[0];
  const float* w1  = (const float*)d_in[1];
  const float* b1  = (const float*)d_in[2];
  const float* g1  = (const float*)d_in[3];
  const float* be1 = (const float*)d_in[4];
  const float* w2  = (const float*)d_in[5];
  const float* b2  = (const float*)d_in[6];
  const float* g2  = (const float*)d_in[7];
  const float* be2 = (const float*)d_in[8];
  const float* opw = (const float*)d_in[9];
  const float* opb = (const float*)d_in[10];
  const float* pw1 = (const float*)d_in[11];
  const float* pb1 = (const float*)d_in[12];
  const float* pg  = (const float*)d_in[13];
  const float* pbe = (const float*)d_in[14];
  const float* pw2 = (const float*)d_in[15];
  const float* pb2 = (const float*)d_in[16];
  float* out = (float*)d_out;
  char*  ws  = (char*)d_ws;

  unsigned short* p2E    = (unsigned short*)(ws + (size_t)32*MB);
  unsigned short* w1p_rp = (unsigned short*)(ws + (size_t)33*MB);
  unsigned short* w2p_rp = (unsigned short*)(ws + (size_t)34*MB);
  unsigned short* opwp   = (unsigned short*)(ws + (size_t)35*MB);
  unsigned short* fh     = (unsigned short*)(ws + (size_t)36*MB);
  unsigned short* fl     = (unsigned short*)(ws + (size_t)44*MB);
  int*            list   = (int*)(ws + (size_t)52*MB);
  int*            cnt    = (int*)(ws + (size_t)54*MB);

  k_pre   <<<897, 256, 0, stream>>>(w1, w2, opw, pw2,
                                    w1p_rp, w2p_rp, opwp, p2E, cnt);
  k_fused <<<256, 1024, 65536, stream>>>(X, w1p_rp, b1, g1, be1,
                                         w2p_rp, b2, g2, be2, opwp, opb,
                                         fh, fl, out, cnt, list);
  k_expert<<<448, 1024, 0, stream>>>(fh, fl, pw1, pb1, pg, pbe, p2E, pb2,
                                     cnt, list, out);
}